// Round 9
// baseline (96.287 us; speedup 1.0000x reference)
//
#include <hip/hip_runtime.h>
#include <hip/hip_bf16.h>

#define C_ 8
#define B_ 32
#define G_ 2048
#define S_ 32
#define L_ 3
#define GB_ (G_ * B_)                 // 65536 items per clause

// R layout (buf0, buf1, xT): bq-major  [c][b/4][g][4]  (xT: [b/4][g][4])
//   flat index inside a clause: bq*8192 + g*4 + (b&3)   (65536 floats per clause)

// ws float offsets
#define OFF_BUF0 0                     // [C][8][G][4] unnormalized R (gather source)
#define OFF_BUF1 524288                // [C][8][G][4] clause lse r
#define OFF_MAX  1048576               // cmax slots: (t*8+c)*16 -> 512 floats
#define OFF_GMAX (OFF_MAX + 512)       // gmax slots: t*16 -> 64 floats
#define OFF_XT   (OFF_MAX + 640)       // xT [8][G][4]
#define ZERO_FLOATS 576

__device__ __forceinline__ void atomicMaxPos(float* a, float v) {
    // all values >= 0, so uint compare == float compare
    atomicMax((unsigned*)a, __float_as_uint(v));
}

// ---- build xT[bq][g][b3] = x[b][g]; zero the max slots ----
__global__ __launch_bounds__(1024) void k_init(const float* __restrict__ x,
                                               float* __restrict__ xT,
                                               float* __restrict__ maxs) {
    __shared__ float sT[32 * 33];
    const int tid = threadIdx.x, bid = blockIdx.x;    // 64 blocks x 1024
    const int g0 = bid * 32;
    // read x coalesced: b = tid>>5, gloc = tid&31
    sT[(tid & 31) * 33 + (tid >> 5)] = x[(tid >> 5) * G_ + g0 + (tid & 31)];
    __syncthreads();
    // write bq-major: gloc = tid>>5, b = tid&31
    {
        const int gloc = tid >> 5, b = tid & 31;
        xT[(b >> 2) * (G_ * 4) + (g0 + gloc) * 4 + (b & 3)] = sT[gloc * 33 + b];
    }
    if (bid == 0 && tid < ZERO_FLOATS) maxs[tid] = 0.0f;
}

// ---- clause: LDS-staged slice gather, normalized-at-staging ----
// 1024 blocks: c = bid>>7, bh(b-quad) = (bid>>4)&7, gs = bid&15 (128 g-rows each)
__global__ __launch_bounds__(256, 4) void k_clause(const float* __restrict__ Rbase,
                                                   int cstride,                 // 0 at t=0
                                                   const int* __restrict__ I,
                                                   float* __restrict__ r_out,   // buf1
                                                   const float* __restrict__ gmax_prev,
                                                   float* __restrict__ cmax_step) {
    __shared__ float sR[G_ * 4];        // 32 KB: this (c, b-quad) slice, NORMALIZED
    __shared__ float sRed[4];

    const int tid = threadIdx.x;
    const int bid = blockIdx.x;
    const int c = bid >> 7;
    const int bh = (bid >> 4) & 7;
    const int gs = bid & 15;

    const float gm = gmax_prev ? gmax_prev[0] : 0.0f;
    const float sc = (gm > 1.0f) ? (1.0f / gm) : 1.0f;

    // stage slice scaled by sc: fully contiguous (bq-major layout), 2048 float4
    {
        const float4* src = (const float4*)(Rbase + c * cstride + bh * (G_ * 4));
        float4* dst = (float4*)sR;
#pragma unroll
        for (int k = 0; k < 8; ++k) {
            float4 v = src[tid + k * 256];
            v.x *= sc; v.y *= sc; v.z *= sc; v.w *= sc;
            dst[tid + k * 256] = v;
        }
    }
    __syncthreads();

    const int bh2 = tid & 1;                       // float2 within the quad
    const float2* sR2 = (const float2*)sR + bh2;   // element g -> sR2[g*2]

    const int row = gs * 128 + (tid >> 1);
    const int4* p = (const int4*)(I + (c * G_ + row) * 96);

    float2 mx = make_float2(-1e30f, -1e30f);
    float2 sum = make_float2(0.0f, 0.0f);
#pragma unroll
    for (int ch = 0; ch < 8; ++ch) {               // 4 substitutions per chunk
        const int4 qa = p[ch * 3 + 0], qb = p[ch * 3 + 1], qc = p[ch * 3 + 2];
        const float2 v0 = sR2[qa.x << 1], v1 = sR2[qa.y << 1], v2 = sR2[qa.z << 1];
        const float2 v3 = sR2[qa.w << 1], v4 = sR2[qb.x << 1], v5 = sR2[qb.y << 1];
        const float2 v6 = sR2[qb.z << 1], v7 = sR2[qb.w << 1], v8 = sR2[qc.x << 1];
        const float2 v9 = sR2[qc.y << 1], va = sR2[qc.z << 1], vb = sR2[qc.w << 1];
        float2 b0, b1, b2, b3;
        b0.x = v0.x * v1.x * v2.x;  b0.y = v0.y * v1.y * v2.y;
        b1.x = v3.x * v4.x * v5.x;  b1.y = v3.y * v4.y * v5.y;
        b2.x = v6.x * v7.x * v8.x;  b2.y = v6.y * v7.y * v8.y;
        b3.x = v9.x * va.x * vb.x;  b3.y = v9.y * va.y * vb.y;
        float2 cm;
        cm.x = fmaxf(fmaxf(b0.x, b1.x), fmaxf(b2.x, b3.x));
        cm.y = fmaxf(fmaxf(b0.y, b1.y), fmaxf(b2.y, b3.y));
        float2 nmx;
        nmx.x = fmaxf(mx.x, cm.x);
        nmx.y = fmaxf(mx.y, cm.y);
        float2 ps;
        ps.x = __expf((b0.x - nmx.x) * 100.0f) + __expf((b1.x - nmx.x) * 100.0f) +
               __expf((b2.x - nmx.x) * 100.0f) + __expf((b3.x - nmx.x) * 100.0f);
        ps.y = __expf((b0.y - nmx.y) * 100.0f) + __expf((b1.y - nmx.y) * 100.0f) +
               __expf((b2.y - nmx.y) * 100.0f) + __expf((b3.y - nmx.y) * 100.0f);
        sum.x = sum.x * __expf((mx.x - nmx.x) * 100.0f) + ps.x;
        sum.y = sum.y * __expf((mx.y - nmx.y) * 100.0f) + ps.y;
        mx = nmx;
    }
    float2 lse;
    lse.x = mx.x + 0.01f * __logf(sum.x);
    lse.y = mx.y + 0.01f * __logf(sum.y);

    // write r in bq-major layout
    *(float2*)(r_out + ((c * 8 + bh) * G_ + row) * 4 + bh2 * 2) = lse;

    // per-clause max partials -> atomic (block is single-clause)
    float m = fmaxf(lse.x, lse.y);
#pragma unroll
    for (int o = 32; o; o >>= 1) m = fmaxf(m, __shfl_xor(m, o, 64));
    const int lane = tid & 63, wv = tid >> 6;
    if (lane == 0) sRed[wv] = m;
    __syncthreads();
    if (tid == 0) {
        float a = fmaxf(fmaxf(sRed[0], sRed[1]), fmaxf(sRed[2], sRed[3]));
        atomicMaxPos(&cmax_step[c * 16], a);
    }
}

// ---- combine: acc = softor2(Rold*sc, r*scr), float4, gmax atomic ----
// elementwise in bq-major layout (c = i >> 16 still holds)
__global__ __launch_bounds__(256, 8) void k_combine(const float* __restrict__ Rold,
                                                    int mask,                     // GB_-1 at t=0
                                                    const float* __restrict__ r_in,
                                                    float* __restrict__ Rnew,     // buf0
                                                    const float* __restrict__ gmax_prev,
                                                    const float* __restrict__ cmax_step,
                                                    float* __restrict__ gmax_out) {
    __shared__ float sRed[4];
    const int tid = threadIdx.x;
    const int i4 = (blockIdx.x * 256 + tid) * 4;     // 512 blocks cover 524288 items
    const int c = i4 >> 16;

    const float gm = gmax_prev ? gmax_prev[0] : 0.0f;
    const float sc = (gm > 1.0f) ? (1.0f / gm) : 1.0f;
    const float cmv = cmax_step[c * 16];
    const float scr = (cmv > 1.0f) ? (1.0f / cmv) : 1.0f;

    const float4 Ro = *(const float4*)(Rold + (i4 & mask));
    const float4 rv = *(const float4*)(r_in + i4);
    float4 o;
    {
        float Rn = Ro.x * sc, rn = rv.x * scr;
        float M = fmaxf(Rn, rn), mn = fminf(Rn, rn);
        o.x = M + 0.01f * __logf(1.0f + __expf((mn - M) * 100.0f));
    }
    {
        float Rn = Ro.y * sc, rn = rv.y * scr;
        float M = fmaxf(Rn, rn), mn = fminf(Rn, rn);
        o.y = M + 0.01f * __logf(1.0f + __expf((mn - M) * 100.0f));
    }
    {
        float Rn = Ro.z * sc, rn = rv.z * scr;
        float M = fmaxf(Rn, rn), mn = fminf(Rn, rn);
        o.z = M + 0.01f * __logf(1.0f + __expf((mn - M) * 100.0f));
    }
    {
        float Rn = Ro.w * sc, rn = rv.w * scr;
        float M = fmaxf(Rn, rn), mn = fminf(Rn, rn);
        o.w = M + 0.01f * __logf(1.0f + __expf((mn - M) * 100.0f));
    }
    *(float4*)(Rnew + i4) = o;

    float mm = fmaxf(fmaxf(o.x, o.y), fmaxf(o.z, o.w));
#pragma unroll
    for (int off = 32; off; off >>= 1) mm = fmaxf(mm, __shfl_xor(mm, off, 64));
    const int lane = tid & 63, wv = tid >> 6;
    if (lane == 0) sRed[wv] = mm;
    __syncthreads();
    if (tid == 0) {
        float a = fmaxf(fmaxf(sRed[0], sRed[1]), fmaxf(sRed[2], sRed[3]));
        atomicMaxPos(gmax_out, a);
    }
}

// ---- out: bq-major [C][8][G][4] -> [C][B][G] with final global-max scale ----
__global__ __launch_bounds__(256) void k_out(const float* __restrict__ buf0,
                                             const float* __restrict__ gmaxslot,
                                             float* __restrict__ out) {
    __shared__ float sT[32 * 65];
    const int bid = blockIdx.x;        // 256 = 8 c x 32 g-chunks of 64
    const int c = bid >> 5;
    const int g0 = (bid & 31) << 6;
    const int tid = threadIdx.x;

    const float gm = gmaxslot[0];
    const float sc = (gm > 1.0f) ? (1.0f / gm) : 1.0f;

    const int r = tid >> 2, w = tid & 3;
#pragma unroll
    for (int k = 0; k < 8; ++k) {      // k = b-quad; reads fully contiguous per k
        sT[(k * 4 + w) * 65 + r] = buf0[((c * 8 + k) * G_ + g0 + r) * 4 + w] * sc;
    }
    __syncthreads();
#pragma unroll
    for (int k = 0; k < 8; ++k) {
        const int j = tid + k * 256;
        const int b = j >> 6, gg = j & 63;
        out[(c * B_ + b) * G_ + g0 + gg] = sT[b * 65 + gg];   // coalesced
    }
}

extern "C" void kernel_launch(void* const* d_in, const int* in_sizes, int n_in,
                              void* d_out, int out_size, void* d_ws, size_t ws_size,
                              hipStream_t stream) {
    const float* x = (const float*)d_in[0];
    const int* I = (const int*)d_in[1];
    float* out = (float*)d_out;
    float* ws = (float*)d_ws;

    float* buf0 = ws + OFF_BUF0;
    float* buf1 = ws + OFF_BUF1;
    float* maxs = ws + OFF_MAX;         // cmax slots
    float* gmax = ws + OFF_GMAX;        // gmax slots
    float* xT = ws + OFF_XT;

    k_init<<<64, 1024, 0, stream>>>(x, xT, maxs);

    for (int t = 0; t < 4; ++t) {
        const float* Rsrc = (t == 0) ? xT : buf0;
        const int cs = (t == 0) ? 0 : GB_;
        const float* gprev = (t == 0) ? nullptr : (gmax + (t - 1) * 16);
        float* cstep = maxs + t * 128;
        const int mask = (t == 0) ? (GB_ - 1) : 0x7FFFFFFF;   // strip clause bits only

        k_clause<<<1024, 256, 0, stream>>>(Rsrc, cs, I, buf1, gprev, cstep);
        k_combine<<<512, 256, 0, stream>>>(Rsrc, mask, buf1, buf0, gprev, cstep,
                                           gmax + t * 16);
    }

    k_out<<<256, 256, 0, stream>>>(buf0, gmax + 48, out);
}

// Round 11
// 95.722 us; speedup vs baseline: 1.0059x; 1.0059x over previous
//
#include <hip/hip_runtime.h>
#include <hip/hip_bf16.h>

#define C_ 8
#define B_ 32
#define G_ 2048
#define S_ 32
#define L_ 3
#define GB_ (G_ * B_)                 // 65536 items per clause

// R layout (buf0, buf1, xT): bq-major  [c][b/4][g][4]  (xT: [b/4][g][4])

// ws float offsets
#define OFF_BUF0 0                     // [C][8][G][4] unnormalized R (gather source)
#define OFF_BUF1 524288                // [C][8][G][4] clause lse r
#define OFF_MAX  1048576               // cmax slots: (t*8+c)*16 -> 512 floats
#define OFF_GMAX (OFF_MAX + 512)       // gmax slots: t*16 -> 64 floats
#define OFF_XT   (OFF_MAX + 640)       // xT [8][G][4]
#define ZERO_FLOATS 576

#define K_SCALE 144.26950408889634f    // 100 * log2(e)
#define GLN2 0.0069314718055994531f    // 0.01 * ln(2)

#define EXP2F(x) __builtin_amdgcn_exp2f(x)   // v_exp_f32: 2^x
#define LOG2F(x) __builtin_amdgcn_logf(x)    // v_log_f32: log2(x)

__device__ __forceinline__ void atomicMaxPos(float* a, float v) {
    // all values >= 0, so uint compare == float compare
    atomicMax((unsigned*)a, __float_as_uint(v));
}

// ---- build xT[bq][g][b3] = x[b][g]; zero the max slots ----
__global__ __launch_bounds__(1024) void k_init(const float* __restrict__ x,
                                               float* __restrict__ xT,
                                               float* __restrict__ maxs) {
    __shared__ float sT[32 * 33];
    const int tid = threadIdx.x, bid = blockIdx.x;    // 64 blocks x 1024
    const int g0 = bid * 32;
    sT[(tid & 31) * 33 + (tid >> 5)] = x[(tid >> 5) * G_ + g0 + (tid & 31)];
    __syncthreads();
    {
        const int gloc = tid >> 5, b = tid & 31;
        xT[(b >> 2) * (G_ * 4) + (g0 + gloc) * 4 + (b & 3)] = sT[gloc * 33 + b];
    }
    if (bid == 0 && tid < ZERO_FLOATS) maxs[tid] = 0.0f;
}

// ---- clause: LDS-staged slice gather, chunk-parallel two-level LSE ----
// 512 blocks: c = bid>>6, bh(b-quad) = (bid>>3)&7, gs = bid&7 (2 passes x 128 rows)
__global__ __launch_bounds__(256, 2) void k_clause(const float* __restrict__ Rbase,
                                                   int cstride,                 // 0 at t=0
                                                   const int* __restrict__ I,
                                                   float* __restrict__ r_out,   // buf1
                                                   const float* __restrict__ gmax_prev,
                                                   float* __restrict__ cmax_step) {
    __shared__ float sR[G_ * 4];        // 32 KB: this (c, b-quad) slice, NORMALIZED
    __shared__ float sRed[4];

    const int tid = threadIdx.x;
    const int bid = blockIdx.x;
    const int c = bid >> 6;
    const int bh = (bid >> 3) & 7;
    const int gs = bid & 7;

    const float gm = gmax_prev ? gmax_prev[0] : 0.0f;
    const float sc = (gm > 1.0f) ? (1.0f / gm) : 1.0f;

    // stage slice scaled by sc: fully contiguous (bq-major layout), 2048 float4
    {
        const float4* src = (const float4*)(Rbase + c * cstride + bh * (G_ * 4));
        float4* dst = (float4*)sR;
#pragma unroll
        for (int k = 0; k < 8; ++k) {
            float4 v = src[tid + k * 256];
            v.x *= sc; v.y *= sc; v.z *= sc; v.w *= sc;
            dst[tid + k * 256] = v;
        }
    }
    __syncthreads();

    const int bh2 = tid & 1;                       // float2 within the quad
    const float2* sR2 = (const float2*)sR + bh2;   // element g -> sR2[g*2]

    float blockm = -1e30f;

#pragma unroll 1
    for (int pass = 0; pass < 2; ++pass) {
        const int row = gs * 256 + pass * 128 + (tid >> 1);
        const int4* p = (const int4*)(I + (c * G_ + row) * 96);

        float2 lm[8], pp[8];
#pragma unroll
        for (int ch = 0; ch < 8; ++ch) {           // 8 INDEPENDENT chunks (4 subs each)
            const int4 qa = p[ch * 3 + 0], qb = p[ch * 3 + 1], qc = p[ch * 3 + 2];
            const float2 v0 = sR2[qa.x << 1], v1 = sR2[qa.y << 1], v2 = sR2[qa.z << 1];
            const float2 v3 = sR2[qa.w << 1], v4 = sR2[qb.x << 1], v5 = sR2[qb.y << 1];
            const float2 v6 = sR2[qb.z << 1], v7 = sR2[qb.w << 1], v8 = sR2[qc.x << 1];
            const float2 v9 = sR2[qc.y << 1], va = sR2[qc.z << 1], vb = sR2[qc.w << 1];
            float2 b0, b1, b2, b3;                 // bodies pre-scaled by K = 100*log2e
            b0.x = v0.x * v1.x * (v2.x * K_SCALE);  b0.y = v0.y * v1.y * (v2.y * K_SCALE);
            b1.x = v3.x * v4.x * (v5.x * K_SCALE);  b1.y = v3.y * v4.y * (v5.y * K_SCALE);
            b2.x = v6.x * v7.x * (v8.x * K_SCALE);  b2.y = v6.y * v7.y * (v8.y * K_SCALE);
            b3.x = v9.x * va.x * (vb.x * K_SCALE);  b3.y = v9.y * va.y * (vb.y * K_SCALE);
            lm[ch].x = fmaxf(fmaxf(b0.x, b1.x), fmaxf(b2.x, b3.x));
            lm[ch].y = fmaxf(fmaxf(b0.y, b1.y), fmaxf(b2.y, b3.y));
            pp[ch].x = EXP2F(b0.x - lm[ch].x) + EXP2F(b1.x - lm[ch].x) +
                       EXP2F(b2.x - lm[ch].x) + EXP2F(b3.x - lm[ch].x);
            pp[ch].y = EXP2F(b0.y - lm[ch].y) + EXP2F(b1.y - lm[ch].y) +
                       EXP2F(b2.y - lm[ch].y) + EXP2F(b3.y - lm[ch].y);
        }
        // combine the 8 partials (tree)
        float2 M;
        M.x = fmaxf(fmaxf(fmaxf(lm[0].x, lm[1].x), fmaxf(lm[2].x, lm[3].x)),
                    fmaxf(fmaxf(lm[4].x, lm[5].x), fmaxf(lm[6].x, lm[7].x)));
        M.y = fmaxf(fmaxf(fmaxf(lm[0].y, lm[1].y), fmaxf(lm[2].y, lm[3].y)),
                    fmaxf(fmaxf(lm[4].y, lm[5].y), fmaxf(lm[6].y, lm[7].y)));
        float2 sum = make_float2(0.0f, 0.0f);
#pragma unroll
        for (int ch = 0; ch < 8; ++ch) {
            sum.x += pp[ch].x * EXP2F(lm[ch].x - M.x);
            sum.y += pp[ch].y * EXP2F(lm[ch].y - M.y);
        }
        float2 lse;
        lse.x = GLN2 * (M.x + LOG2F(sum.x));
        lse.y = GLN2 * (M.y + LOG2F(sum.y));

        // write r in bq-major layout
        *(float2*)(r_out + ((c * 8 + bh) * G_ + row) * 4 + bh2 * 2) = lse;
        blockm = fmaxf(blockm, fmaxf(lse.x, lse.y));
    }

    // per-clause max partials -> atomic (block is single-clause)
    float m = blockm;
#pragma unroll
    for (int o = 32; o; o >>= 1) m = fmaxf(m, __shfl_xor(m, o, 64));
    const int lane = tid & 63, wv = tid >> 6;
    if (lane == 0) sRed[wv] = m;
    __syncthreads();
    if (tid == 0) {
        float a = fmaxf(fmaxf(sRed[0], sRed[1]), fmaxf(sRed[2], sRed[3]));
        atomicMaxPos(&cmax_step[c * 16], a);
    }
}

// ---- combine: acc = softor2(Rold*sc, r*scr), float4, gmax atomic ----
__global__ __launch_bounds__(256, 8) void k_combine(const float* __restrict__ Rold,
                                                    int mask,                     // GB_-1 at t=0
                                                    const float* __restrict__ r_in,
                                                    float* __restrict__ Rnew,     // buf0
                                                    const float* __restrict__ gmax_prev,
                                                    const float* __restrict__ cmax_step,
                                                    float* __restrict__ gmax_out) {
    __shared__ float sRed[4];
    const int tid = threadIdx.x;
    const int i4 = (blockIdx.x * 256 + tid) * 4;     // 512 blocks cover 524288 items
    const int c = i4 >> 16;

    const float gm = gmax_prev ? gmax_prev[0] : 0.0f;
    const float sc = (gm > 1.0f) ? (1.0f / gm) : 1.0f;
    const float cmv = cmax_step[c * 16];
    const float scr = (cmv > 1.0f) ? (1.0f / cmv) : 1.0f;

    const float4 Ro = *(const float4*)(Rold + (i4 & mask));
    const float4 rv = *(const float4*)(r_in + i4);
    float4 o;
    {
        float Rn = Ro.x * sc, rn = rv.x * scr;
        float M = fmaxf(Rn, rn), mn = fminf(Rn, rn);
        o.x = M + 0.01f * __logf(1.0f + __expf((mn - M) * 100.0f));
    }
    {
        float Rn = Ro.y * sc, rn = rv.y * scr;
        float M = fmaxf(Rn, rn), mn = fminf(Rn, rn);
        o.y = M + 0.01f * __logf(1.0f + __expf((mn - M) * 100.0f));
    }
    {
        float Rn = Ro.z * sc, rn = rv.z * scr;
        float M = fmaxf(Rn, rn), mn = fminf(Rn, rn);
        o.z = M + 0.01f * __logf(1.0f + __expf((mn - M) * 100.0f));
    }
    {
        float Rn = Ro.w * sc, rn = rv.w * scr;
        float M = fmaxf(Rn, rn), mn = fminf(Rn, rn);
        o.w = M + 0.01f * __logf(1.0f + __expf((mn - M) * 100.0f));
    }
    *(float4*)(Rnew + i4) = o;

    float mm = fmaxf(fmaxf(o.x, o.y), fmaxf(o.z, o.w));
#pragma unroll
    for (int off = 32; off; off >>= 1) mm = fmaxf(mm, __shfl_xor(mm, off, 64));
    const int lane = tid & 63, wv = tid >> 6;
    if (lane == 0) sRed[wv] = mm;
    __syncthreads();
    if (tid == 0) {
        float a = fmaxf(fmaxf(sRed[0], sRed[1]), fmaxf(sRed[2], sRed[3]));
        atomicMaxPos(gmax_out, a);
    }
}

// ---- out: bq-major [C][8][G][4] -> [C][B][G] with final global-max scale ----
__global__ __launch_bounds__(256) void k_out(const float* __restrict__ buf0,
                                             const float* __restrict__ gmaxslot,
                                             float* __restrict__ out) {
    __shared__ float sT[32 * 65];
    const int bid = blockIdx.x;        // 256 = 8 c x 32 g-chunks of 64
    const int c = bid >> 5;
    const int g0 = (bid & 31) << 6;
    const int tid = threadIdx.x;

    const float gm = gmaxslot[0];
    const float sc = (gm > 1.0f) ? (1.0f / gm) : 1.0f;

    const int r = tid >> 2, w = tid & 3;
#pragma unroll
    for (int k = 0; k < 8; ++k) {      // k = b-quad; reads fully contiguous per k
        sT[(k * 4 + w) * 65 + r] = buf0[((c * 8 + k) * G_ + g0 + r) * 4 + w] * sc;
    }
    __syncthreads();
#pragma unroll
    for (int k = 0; k < 8; ++k) {
        const int j = tid + k * 256;
        const int b = j >> 6, gg = j & 63;
        out[(c * B_ + b) * G_ + g0 + gg] = sT[b * 65 + gg];   // coalesced
    }
}

extern "C" void kernel_launch(void* const* d_in, const int* in_sizes, int n_in,
                              void* d_out, int out_size, void* d_ws, size_t ws_size,
                              hipStream_t stream) {
    const float* x = (const float*)d_in[0];
    const int* I = (const int*)d_in[1];
    float* out = (float*)d_out;
    float* ws = (float*)d_ws;

    float* buf0 = ws + OFF_BUF0;
    float* buf1 = ws + OFF_BUF1;
    float* maxs = ws + OFF_MAX;         // cmax slots
    float* gmax = ws + OFF_GMAX;        // gmax slots
    float* xT = ws + OFF_XT;

    k_init<<<64, 1024, 0, stream>>>(x, xT, maxs);

    for (int t = 0; t < 4; ++t) {
        const float* Rsrc = (t == 0) ? xT : buf0;
        const int cs = (t == 0) ? 0 : GB_;
        const float* gprev = (t == 0) ? nullptr : (gmax + (t - 1) * 16);
        float* cstep = maxs + t * 128;
        const int mask = (t == 0) ? (GB_ - 1) : 0x7FFFFFFF;   // strip clause bits only

        k_clause<<<512, 256, 0, stream>>>(Rsrc, cs, I, buf1, gprev, cstep);
        k_combine<<<512, 256, 0, stream>>>(Rsrc, mask, buf1, buf0, gprev, cstep,
                                           gmax + t * 16);
    }

    k_out<<<256, 256, 0, stream>>>(buf0, gmax + 48, out);
}

// Round 12
// 94.439 us; speedup vs baseline: 1.0196x; 1.0136x over previous
//
#include <hip/hip_runtime.h>
#include <hip/hip_bf16.h>

#define C_ 8
#define B_ 32
#define G_ 2048
#define S_ 32
#define L_ 3
#define GB_ (G_ * B_)                 // 65536 items per clause

// R layout (buf0, buf1): bq-major  [c][b/4][g][4]
//   flat index inside a clause: bq*8192 + g*4 + (b&3)

// ws float offsets
#define OFF_BUF0 0                     // [C][8][G][4] unnormalized R (gather source)
#define OFF_BUF1 524288                // [C][8][G][4] clause lse r
#define OFF_MAX  1048576               // cmax slots: (t*8+c)*16 -> 512 floats
#define OFF_GMAX (OFF_MAX + 512)       // gmax slots: t*16 -> 64 floats
#define ZERO_FLOATS 576

#define K_SCALE 144.26950408889634f    // 100 * log2(e)
#define GLN2 0.0069314718055994531f    // 0.01 * ln(2)

#define EXP2F(x) __builtin_amdgcn_exp2f(x)   // v_exp_f32: 2^x
#define LOG2F(x) __builtin_amdgcn_logf(x)    // v_log_f32: log2(x)

__device__ __forceinline__ void atomicMaxPos(float* a, float v) {
    // all values >= 0, so uint compare == float compare
    atomicMax((unsigned*)a, __float_as_uint(v));
}

__device__ __forceinline__ float4 body3(float4 a, float4 b, float4 c) {
    float4 r;
    r.x = a.x * b.x * (c.x * K_SCALE);
    r.y = a.y * b.y * (c.y * K_SCALE);
    r.z = a.z * b.z * (c.z * K_SCALE);
    r.w = a.w * b.w * (c.w * K_SCALE);
    return r;
}
__device__ __forceinline__ float4 fmax4v(float4 a, float4 b) {
    float4 r;
    r.x = fmaxf(a.x, b.x); r.y = fmaxf(a.y, b.y);
    r.z = fmaxf(a.z, b.z); r.w = fmaxf(a.w, b.w);
    return r;
}
__device__ __forceinline__ float4 exp2m(float4 a, float4 m) {   // 2^(a-m)
    float4 r;
    r.x = EXP2F(a.x - m.x); r.y = EXP2F(a.y - m.y);
    r.z = EXP2F(a.z - m.z); r.w = EXP2F(a.w - m.w);
    return r;
}

// ---- clause: LDS-staged slice gather, float4 (4 b) per thread, 1 row/thread ----
// 512 blocks: c = bid>>6, bh(b-quad) = (bid>>3)&7, gs = bid&7 (256 rows each)
__global__ __launch_bounds__(256, 2) void k_clause(const float* __restrict__ Rbase,
                                                   int xmode,                   // 1 at t=0: Rbase = x
                                                   const int* __restrict__ I,
                                                   float* __restrict__ r_out,   // buf1
                                                   const float* __restrict__ gmax_prev,
                                                   float* __restrict__ cmax_step) {
    __shared__ float sR[G_ * 4];        // 32 KB: this (c, b-quad) slice, NORMALIZED
    __shared__ float sRed[4];

    const int tid = threadIdx.x;
    const int bid = blockIdx.x;
    const int c = bid >> 6;
    const int bh = (bid >> 3) & 7;
    const int gs = bid & 7;

    const float gm = gmax_prev ? gmax_prev[0] : 0.0f;
    const float sc = (gm > 1.0f) ? (1.0f / gm) : 1.0f;

    if (xmode) {
        // transpose-stage from x: sR[g*4+j] = x[(bh*4+j)*G + g]  (sc == 1 at t=0)
        const int j = tid >> 6;
        const int g0 = tid & 63;
        const float* xr = Rbase + (bh * 4 + j) * G_;
#pragma unroll
        for (int k = 0; k < 32; ++k) {
            const int g = g0 + 64 * k;
            sR[g * 4 + j] = xr[g];
        }
    } else {
        const float4* src = (const float4*)(Rbase + c * GB_ + bh * (G_ * 4));
        float4* dst = (float4*)sR;
#pragma unroll
        for (int k = 0; k < 8; ++k) {
            float4 v = src[tid + k * 256];
            v.x *= sc; v.y *= sc; v.z *= sc; v.w *= sc;
            dst[tid + k * 256] = v;
        }
    }
    __syncthreads();

    const float4* sR4 = (const float4*)sR;
    const int row = gs * 256 + tid;
    const int4* p = (const int4*)(I + (c * G_ + row) * 96);

    float4 lm[8], pp[8];
#pragma unroll
    for (int ch = 0; ch < 8; ++ch) {    // 8 independent chunks of 4 substitutions
        const int4 qa = p[ch * 3 + 0], qb = p[ch * 3 + 1], qc = p[ch * 3 + 2];
        const float4 b0 = body3(sR4[qa.x], sR4[qa.y], sR4[qa.z]);
        const float4 b1 = body3(sR4[qa.w], sR4[qb.x], sR4[qb.y]);
        const float4 b2 = body3(sR4[qb.z], sR4[qb.w], sR4[qc.x]);
        const float4 b3 = body3(sR4[qc.y], sR4[qc.z], sR4[qc.w]);
        const float4 l = fmax4v(fmax4v(b0, b1), fmax4v(b2, b3));
        const float4 e0 = exp2m(b0, l), e1 = exp2m(b1, l);
        const float4 e2 = exp2m(b2, l), e3 = exp2m(b3, l);
        float4 s;
        s.x = e0.x + e1.x + e2.x + e3.x;
        s.y = e0.y + e1.y + e2.y + e3.y;
        s.z = e0.z + e1.z + e2.z + e3.z;
        s.w = e0.w + e1.w + e2.w + e3.w;
        lm[ch] = l; pp[ch] = s;
    }
    // two-level combine (tree)
    float4 M = fmax4v(fmax4v(fmax4v(lm[0], lm[1]), fmax4v(lm[2], lm[3])),
                      fmax4v(fmax4v(lm[4], lm[5]), fmax4v(lm[6], lm[7])));
    float4 sum = make_float4(0.f, 0.f, 0.f, 0.f);
#pragma unroll
    for (int ch = 0; ch < 8; ++ch) {
        const float4 w = exp2m(lm[ch], M);
        sum.x += pp[ch].x * w.x; sum.y += pp[ch].y * w.y;
        sum.z += pp[ch].z * w.z; sum.w += pp[ch].w * w.w;
    }
    float4 lse;
    lse.x = GLN2 * (M.x + LOG2F(sum.x));
    lse.y = GLN2 * (M.y + LOG2F(sum.y));
    lse.z = GLN2 * (M.z + LOG2F(sum.z));
    lse.w = GLN2 * (M.w + LOG2F(sum.w));

    // write r in bq-major layout: perfect b128 store, coalesced across threads
    *(float4*)(r_out + ((c * 8 + bh) * G_ + row) * 4) = lse;

    // per-clause max partials -> atomic (block is single-clause)
    float m = fmaxf(fmaxf(lse.x, lse.y), fmaxf(lse.z, lse.w));
#pragma unroll
    for (int o = 32; o; o >>= 1) m = fmaxf(m, __shfl_xor(m, o, 64));
    const int lane = tid & 63, wv = tid >> 6;
    if (lane == 0) sRed[wv] = m;
    __syncthreads();
    if (tid == 0) {
        float a = fmaxf(fmaxf(sRed[0], sRed[1]), fmaxf(sRed[2], sRed[3]));
        atomicMaxPos(&cmax_step[c * 16], a);
    }
}

// ---- combine: acc = softor2(Rold*sc, r*scr), float4, gmax atomic ----
__global__ __launch_bounds__(256, 8) void k_combine(const float* __restrict__ Rold,
                                                    int xmode,                    // 1 at t=0: Rold = x
                                                    const float* __restrict__ r_in,
                                                    float* __restrict__ Rnew,     // buf0
                                                    const float* __restrict__ gmax_prev,
                                                    const float* __restrict__ cmax_step,
                                                    float* __restrict__ gmax_out) {
    __shared__ float sRed[4];
    const int tid = threadIdx.x;
    const int i4 = (blockIdx.x * 256 + tid) * 4;     // 512 blocks cover 524288 items
    const int c = i4 >> 16;

    const float gm = gmax_prev ? gmax_prev[0] : 0.0f;
    const float sc = (gm > 1.0f) ? (1.0f / gm) : 1.0f;
    const float cmv = cmax_step[c * 16];
    const float scr = (cmv > 1.0f) ? (1.0f / cmv) : 1.0f;

    float4 Ro;
    if (xmode) {
        const int w = i4 & (GB_ - 1);
        const int bq = w >> 13;
        const int g = (w & 8191) >> 2;
        Ro.x = Rold[(bq * 4 + 0) * G_ + g];
        Ro.y = Rold[(bq * 4 + 1) * G_ + g];
        Ro.z = Rold[(bq * 4 + 2) * G_ + g];
        Ro.w = Rold[(bq * 4 + 3) * G_ + g];
    } else {
        Ro = *(const float4*)(Rold + i4);
    }
    const float4 rv = *(const float4*)(r_in + i4);
    float4 o;
    {
        float Rn = Ro.x * sc, rn = rv.x * scr;
        float M = fmaxf(Rn, rn), mn = fminf(Rn, rn);
        o.x = M + 0.01f * __logf(1.0f + __expf((mn - M) * 100.0f));
    }
    {
        float Rn = Ro.y * sc, rn = rv.y * scr;
        float M = fmaxf(Rn, rn), mn = fminf(Rn, rn);
        o.y = M + 0.01f * __logf(1.0f + __expf((mn - M) * 100.0f));
    }
    {
        float Rn = Ro.z * sc, rn = rv.z * scr;
        float M = fmaxf(Rn, rn), mn = fminf(Rn, rn);
        o.z = M + 0.01f * __logf(1.0f + __expf((mn - M) * 100.0f));
    }
    {
        float Rn = Ro.w * sc, rn = rv.w * scr;
        float M = fmaxf(Rn, rn), mn = fminf(Rn, rn);
        o.w = M + 0.01f * __logf(1.0f + __expf((mn - M) * 100.0f));
    }
    *(float4*)(Rnew + i4) = o;

    float mm = fmaxf(fmaxf(o.x, o.y), fmaxf(o.z, o.w));
#pragma unroll
    for (int off = 32; off; off >>= 1) mm = fmaxf(mm, __shfl_xor(mm, off, 64));
    const int lane = tid & 63, wv = tid >> 6;
    if (lane == 0) sRed[wv] = mm;
    __syncthreads();
    if (tid == 0) {
        float a = fmaxf(fmaxf(sRed[0], sRed[1]), fmaxf(sRed[2], sRed[3]));
        atomicMaxPos(gmax_out, a);
    }
}

// ---- out: bq-major [C][8][G][4] -> [C][B][G] with final global-max scale ----
__global__ __launch_bounds__(256) void k_out(const float* __restrict__ buf0,
                                             const float* __restrict__ gmaxslot,
                                             float* __restrict__ out) {
    __shared__ float sT[32 * 65];
    const int bid = blockIdx.x;        // 256 = 8 c x 32 g-chunks of 64
    const int c = bid >> 5;
    const int g0 = (bid & 31) << 6;
    const int tid = threadIdx.x;

    const float gm = gmaxslot[0];
    const float sc = (gm > 1.0f) ? (1.0f / gm) : 1.0f;

    const int r = tid >> 2, w = tid & 3;
#pragma unroll
    for (int k = 0; k < 8; ++k) {      // k = b-quad; reads fully contiguous per k
        sT[(k * 4 + w) * 65 + r] = buf0[((c * 8 + k) * G_ + g0 + r) * 4 + w] * sc;
    }
    __syncthreads();
#pragma unroll
    for (int k = 0; k < 8; ++k) {
        const int j = tid + k * 256;
        const int b = j >> 6, gg = j & 63;
        out[(c * B_ + b) * G_ + g0 + gg] = sT[b * 65 + gg];   // coalesced
    }
}

extern "C" void kernel_launch(void* const* d_in, const int* in_sizes, int n_in,
                              void* d_out, int out_size, void* d_ws, size_t ws_size,
                              hipStream_t stream) {
    const float* x = (const float*)d_in[0];
    const int* I = (const int*)d_in[1];
    float* out = (float*)d_out;
    float* ws = (float*)d_ws;

    float* buf0 = ws + OFF_BUF0;
    float* buf1 = ws + OFF_BUF1;
    float* maxs = ws + OFF_MAX;         // cmax slots
    float* gmax = ws + OFF_GMAX;        // gmax slots

    hipMemsetAsync(ws + OFF_MAX, 0, ZERO_FLOATS * sizeof(float), stream);

    for (int t = 0; t < 4; ++t) {
        const float* Rsrc = (t == 0) ? x : buf0;
        const int xmode = (t == 0) ? 1 : 0;
        const float* gprev = (t == 0) ? nullptr : (gmax + (t - 1) * 16);
        float* cstep = maxs + t * 128;

        k_clause<<<512, 256, 0, stream>>>(Rsrc, xmode, I, buf1, gprev, cstep);
        k_combine<<<512, 256, 0, stream>>>(Rsrc, xmode, buf1, buf0, gprev, cstep,
                                           gmax + t * 16);
    }

    k_out<<<256, 256, 0, stream>>>(buf0, gmax + 48, out);
}